// Round 4
// baseline (174.527 us; speedup 1.0000x reference)
//
#include <hip/hip_runtime.h>

#define NB 512
#define NT 512
#define NL 64
#define L2E 1.4426950408889634f   // log2(e)
#define LN2 0.6931471805599453f   // ln(2)

__global__ void zero_out_kernel(float* out) { *out = 0.0f; }

// R14: RAW prefetch ring -- kill the per-step HBM-latency stall.
// R11-R13 post-mortem: chain surgery changed issue mix (VALUBusy 29->46->54%)
// but time stayed 755-905 cy/step across ALL variants ~= one HBM miss
// latency (~900 cy). Cause: the prefetch was written `pf[u] = L2E * load`,
// a multiply AT the load site; pf[u] is loop-carried, so the mul (and its
// s_waitcnt) must retire before the back-edge -> every step waits on a
// just-issued load. Fix: the ring stores the RAW loaded value (no consumer
// for 8 steps, ~2000 issue-cy of slack > 900 cy miss latency); L2E* and
// exp2 happen at the USE site. Mask-row ballot inputs likewise prefetched
// one 64-step block ahead. Clamps dropped (t+8 <= 263 fwd / t-8 >= 248 bwd,
// both in-bounds). Engine (R13 DPP row_ror f32 FMA matvec, direction-probed
// permutation, permlane16/32 self-swap reduce, every-4-step exact rescale,
// integer-G bookkeeping, fwd/bwd T/2 split, junction) kept verbatim.

template <int K>
__device__ __forceinline__ unsigned roru(unsigned x) {
  if constexpr (K == 0) return x;
  else
    return (unsigned)__builtin_amdgcn_mov_dpp((int)x, 0x120 + K, 0xF, 0xF, true);
}
template <int K>
__device__ __forceinline__ float rorf(float x) {
  return __uint_as_float(roru<K>(__float_as_uint(x)));
}

__device__ __forceinline__ float pairsum16(float x) {
#if __has_builtin(__builtin_amdgcn_permlane16_swap)
  unsigned xu = __float_as_uint(x);
  auto rp = __builtin_amdgcn_permlane16_swap(xu, xu, false, false);
  return __uint_as_float(rp[0]) + __uint_as_float(rp[1]);
#else
  return x + __shfl_xor(x, 16, 64);
#endif
}
__device__ __forceinline__ float pairsum32(float x) {
#if __has_builtin(__builtin_amdgcn_permlane32_swap)
  unsigned xu = __float_as_uint(x);
  auto rp = __builtin_amdgcn_permlane32_swap(xu, xu, false, false);
  return __uint_as_float(rp[0]) + __uint_as_float(rp[1]);
#else
  return x + __shfl_xor(x, 32, 64);
#endif
}

// y_out(16q+c) partials over input block r, then cross-r reduce; select q==r.
__device__ __forceinline__ float matvec64f(float s, const float (&ep)[4][16],
                                           int r) {
  float A0 = 0.f, A1 = 0.f, A2 = 0.f, A3 = 0.f;
  float B0 = 0.f, B1 = 0.f, B2 = 0.f, B3 = 0.f;
#define MAC2(K0, K1)                                   \
  {                                                    \
    float ta = rorf<K0>(s), tb = rorf<K1>(s);          \
    A0 = fmaf(ta, ep[0][K0], A0);                      \
    B0 = fmaf(tb, ep[0][K1], B0);                      \
    A1 = fmaf(ta, ep[1][K0], A1);                      \
    B1 = fmaf(tb, ep[1][K1], B1);                      \
    A2 = fmaf(ta, ep[2][K0], A2);                      \
    B2 = fmaf(tb, ep[2][K1], B2);                      \
    A3 = fmaf(ta, ep[3][K0], A3);                      \
    B3 = fmaf(tb, ep[3][K1], B3);                      \
  }
  MAC2(0, 1) MAC2(2, 3) MAC2(4, 5) MAC2(6, 7)
  MAC2(8, 9) MAC2(10, 11) MAC2(12, 13) MAC2(14, 15)
#undef MAC2
  float F0 = pairsum32(pairsum16(A0 + B0));
  float F1 = pairsum32(pairsum16(A1 + B1));
  float F2 = pairsum32(pairsum16(A2 + B2));
  float F3 = pairsum32(pairsum16(A3 + B3));
  float ya = (r & 1) ? F1 : F0;
  float yb = (r & 1) ? F3 : F2;
  return (r & 2) ? yb : ya;
}

__device__ __forceinline__ void rescale4(float& s, int& G) {
  unsigned e0 =
      (__builtin_amdgcn_readfirstlane(__float_as_uint(s)) >> 23) & 0xffu;
  s *= __uint_as_float((254u - e0) << 23);  // 2^(127-e0), exact
  G += (int)e0 - 127;
}

__global__
__attribute__((amdgpu_flat_work_group_size(128, 128), amdgpu_waves_per_eu(1, 1)))
void crf_nll_kernel(
    const float* __restrict__ emission,     // B,T,L
    const int*   __restrict__ target,       // B,T
    const float* __restrict__ mask,         // B,T
    const float* __restrict__ start_trans,  // L
    const float* __restrict__ trans,        // L,L
    const float* __restrict__ end_trans,    // L
    float* __restrict__ out)
{
  const int b = blockIdx.x;
  const int tid = threadIdx.x;
  const int wv = tid >> 6;            // 0 = forward, 1 = backward
  const int j = tid & 63;
  const int r = j >> 4;
  const int c = j & 15;

  const float* em_b = emission + (size_t)b * NT * NL;
  const float* mk_b = mask + (size_t)b * NT;
  const int*   tg_b = target + (size_t)b * NT;

  __shared__ float fF[NL], fB[NL];
  __shared__ float psS[2];
  __shared__ int   GS[2];

  // ---- probe the actual row_ror permutation: pi[k] = source column of
  // ---- lane (r,c) under rorf<k>. Direction-proof by construction.
  int pi[16];
  pi[0] = c;
#define PRB(K) pi[K] = (int)roru<K>((unsigned)c);
  PRB(1) PRB(2) PRB(3) PRB(4) PRB(5) PRB(6) PRB(7) PRB(8)
  PRB(9) PRB(10) PRB(11) PRB(12) PRB(13) PRB(14) PRB(15)
#undef PRB

  // ------- path score: wave wv covers chunks [4wv, 4wv+4) = its T half -----
  float ps = 0.0f;
  #pragma unroll
  for (int cc = 4 * wv; cc < 4 * wv + 4; ++cc) {
    int t = cc * 64 + j;
    int cur = tg_b[t];
    float m  = mk_b[t];
    float mn = (t + 1 < NT) ? mk_b[t + 1] : 0.0f;
    if (t == 0) {
      ps += start_trans[cur] + em_b[cur];
    } else {
      int prev = tg_b[t - 1];
      if (m > 0.5f)
        ps += trans[prev * NL + cur] + em_b[(size_t)t * NL + cur];
      if (m - mn > 0.5f)                 // end_mask = m_t & !m_{t+1}
        ps += end_trans[cur];
    }
  }
  #pragma unroll
  for (int off = 32; off; off >>= 1) ps += __shfl_down(ps, off, 64);

  const float endt = __builtin_amdgcn_exp2f(L2E * end_trans[j]);

  int G = 0;          // exact integer scale deficit (log2 units): true = s*2^G
  float s;

  if (wv == 0) {
    // ======================= FORWARD: t = 0..255 ===========================
    // y = E^T s: ep[q][k] = exp(trans[16r + pi[k]][16q + c])
    float ep[4][16];
    #pragma unroll
    for (int q = 0; q < 4; ++q) {
      const int col = 16 * q + c;
      #pragma unroll
      for (int k = 0; k < 16; ++k)
        ep[q][k] = __builtin_amdgcn_exp2f(L2E * trans[(16 * r + pi[k]) * NL + col]);
    }
    s = __builtin_amdgcn_exp2f(L2E * (start_trans[j] + em_b[j]));  // t=0

    // raw prefetch ring: pfr[u] = em[t][j] for upcoming step t (t&7 == u)
    float pfr[8];
    #pragma unroll
    for (int u = 0; u < 8; ++u) pfr[u] = em_b[(size_t)u * NL + j];

    // mask-block pipeline: ballot inputs for cc, prefetched one block ahead
    float mlv = mk_b[j];
    float mnv = mk_b[j + 1];

    #pragma unroll 1
    for (int cc = 0; cc < 4; ++cc) {
      const int tb = cc * 64;
      unsigned long long cm = __ballot(mlv > 0.5f);
      unsigned long long ce = __ballot(mlv - mnv > 0.5f);
      if (cc == 0) { cm &= ~1ull; ce &= ~1ull; }  // t=0 handled by init
      // raw prefetch next block's mask rows (consumed 64 steps later);
      // max index = 3*64+64+63+1 = 320 < NT, always in-bounds.
      mlv = mk_b[tb + 64 + j];
      mnv = mk_b[tb + 64 + j + 1];

      #pragma unroll 1
      for (int i8 = 0; i8 < 64; i8 += 8) {
        #pragma unroll
        for (int u = 0; u < 8; ++u) {
          const int i = i8 + u;
          const int t = tb + i;
          // use value loaded 8 steps ago; refill slot raw (no consumer
          // for 8 steps; t+8 <= 263 < NT, in-bounds)
          float pv = pfr[u];
          pfr[u] = em_b[(size_t)(t + 8) * NL + j];
          float eemu = __builtin_amdgcn_exp2f(L2E * pv);
          eemu = ((ce >> i) & 1) ? eemu * endt : eemu;
          // chain: DPP-fused f32 matvec -> eem mul -> select
          float sm = matvec64f(s, ep, r) * eemu;
          s = ((cm >> i) & 1) ? sm : s;
          if ((u & 3) == 3) rescale4(s, G);      // every 4th step
        }
      }
    }
  } else {
    // ======================= BACKWARD: t = 511..256 ========================
    // v' = E (v o w): epb[q][k] = exp(trans[16q + c][16r + pi[k]])
    float ep[4][16];
    #pragma unroll
    for (int q = 0; q < 4; ++q) {
      const int rowi = 16 * q + c;
      #pragma unroll
      for (int k = 0; k < 16; ++k)
        ep[q][k] = __builtin_amdgcn_exp2f(L2E * trans[rowi * NL + 16 * r + pi[k]]);
    }
    s = 1.0f;                                   // v^T = 1^T

    // raw prefetch ring: slot t&7; boot covers steps 511..504
    float pfr[8];
    #pragma unroll
    for (int u = 0; u < 8; ++u) pfr[u] = em_b[(size_t)(504 + u) * NL + j];

    // mask-block pipeline for cc=7 (guard: 448+j+1 can hit NT)
    float mlv = mk_b[448 + j];
    int nidx0 = 448 + j + 1;
    float mnv = (nidx0 < NT) ? mk_b[nidx0] : 0.0f;

    #pragma unroll 1
    for (int cc = 7; cc >= 4; --cc) {
      const int tb = cc * 64;
      unsigned long long cm = __ballot(mlv > 0.5f);
      unsigned long long ce = __ballot(mlv - mnv > 0.5f);
      // raw prefetch previous block's mask rows (cc-1; min index 192,
      // max 192+63+1 = 256 < NT -- always in-bounds)
      mlv = mk_b[tb - 64 + j];
      mnv = mk_b[tb - 64 + j + 1];

      #pragma unroll 1
      for (int i8 = 56; i8 >= 0; i8 -= 8) {
        #pragma unroll
        for (int u = 7; u >= 0; --u) {
          const int i = i8 + u;
          const int t = tb + i;                  // t & 7 == u
          // use value loaded 8 steps ago; refill slot raw (t-8 >= 248 >= 0)
          float pv = pfr[u];
          pfr[u] = em_b[(size_t)(t - 8) * NL + j];
          float eemu = __builtin_amdgcn_exp2f(L2E * pv);
          float wmul = ((cm >> i) & 1) ? eemu : 1.0f;
          wmul = ((ce >> i) & 1) ? wmul * endt : wmul;
          // chain: w = s*wmul -> matvec (uniform branch) -> rescale
          float w = s * wmul;
          if ((cm >> i) & 1) s = matvec64f(w, ep, r);
          else               s = w;              // A_t = I (masked-out step)
          if ((u & 3) == 0) rescale4(s, G);      // every 4th step
        }
      }
    }
  }

  // ---------------- junction: norm = log(v . q) + (Gf+Gb)*ln2 ---------------
  if (wv == 0) { fF[j] = s; if (j == 0) { psS[0] = ps; GS[0] = G; } }
  else         { fB[j] = s; if (j == 0) { psS[1] = ps; GS[1] = G; } }
  __syncthreads();
  if (wv == 0) {
    float prod = s * fB[j];
    #pragma unroll
    for (int off = 32; off; off >>= 1) prod += __shfl_xor(prod, off, 64);
    if (j == 0) {
      float norm = (__builtin_amdgcn_logf(prod) + (float)(GS[0] + GS[1])) * LN2;
      atomicAdd(out, (norm - psS[0] - psS[1]) * (1.0f / (float)NB));
    }
  }
}

extern "C" void kernel_launch(void* const* d_in, const int* in_sizes, int n_in,
                              void* d_out, int out_size, void* d_ws, size_t ws_size,
                              hipStream_t stream) {
  const float* emission    = (const float*)d_in[0];
  const int*   target      = (const int*)  d_in[1];
  const float* mask        = (const float*)d_in[2];
  const float* start_trans = (const float*)d_in[3];
  const float* trans       = (const float*)d_in[4];
  const float* end_trans   = (const float*)d_in[5];
  float* out = (float*)d_out;

  zero_out_kernel<<<1, 1, 0, stream>>>(out);
  crf_nll_kernel<<<NB, 128, 0, stream>>>(emission, target, mask, start_trans,
                                         trans, end_trans, out);
}

// Round 6
// 166.483 us; speedup vs baseline: 1.0483x; 1.0483x over previous
//
#include <hip/hip_runtime.h>

#define NB 512
#define NT 512
#define NL 64
#define L2E 1.4426950408889634f   // log2(e)
#define LN2 0.6931471805599453f   // ln(2)

typedef _Float16 h2 __attribute__((ext_vector_type(2)));

__global__ void zero_out_kernel(float* out) { *out = 0.0f; }

// R15b: R15 with the cvt_pkrtz return-type fixed (bit_cast from the
// builtin's __fp16-vector to our _Float16-vector; bit-identical).
// R15 theory: time tracks VALU instruction count (~8-10 cy/instr at
// 1 wave/EU) across R10-R14; chain-depth (R12) and memory-latency (R14)
// theories falsified. So: cut instructions. Step = pack-once packed-DPP
// gather (9 instrs) + 32 dot2 in 8x depth-4 chains + verified
// permlane16/32 self-swap reduce + R12's per-step exact rescale.
//  - gather: p0 = cvt_pkrtz(s, ror1(s)); pm = mov_dpp row_ror:2m of the
//    PACKED u32 -> lane c receives (s[sig2m(c)], s[sig1(sig2m(c))]).
//    Both index maps are PROBED at prologue by pushing c through the same
//    DPP net -- correct for either rotation direction.
//  - ep[q][m] = h2(exp(trans[row e0][col]), exp(trans[row e1][col]))
//    matches the pair order; 32 VGPRs.
// Everything else (mask ballots, raw prefetch ring, path score, fwd/bwd
// T/2 split, junction, integer-G bookkeeping) kept verbatim from R14.

template <int K>
__device__ __forceinline__ unsigned roru(unsigned x) {
  if constexpr (K == 0) return x;
  else
    return (unsigned)__builtin_amdgcn_mov_dpp((int)x, 0x120 + K, 0xF, 0xF, true);
}

__device__ __forceinline__ float dot2f(h2 a, h2 b, float c) {
#if __has_builtin(__builtin_amdgcn_fdot2)
  return __builtin_amdgcn_fdot2(a, b, c, false);
#else
  return fmaf((float)a[0], (float)b[0], fmaf((float)a[1], (float)b[1], c));
#endif
}

__device__ __forceinline__ h2 pkrtz(float a, float b) {
#if __has_builtin(__builtin_amdgcn_cvt_pkrtz)
  return __builtin_bit_cast(h2, __builtin_amdgcn_cvt_pkrtz(a, b));
#else
  h2 v; v[0] = (_Float16)a; v[1] = (_Float16)b; return v;
#endif
}

__device__ __forceinline__ float pairsum16(float x) {
#if __has_builtin(__builtin_amdgcn_permlane16_swap)
  unsigned xu = __float_as_uint(x);
  auto rp = __builtin_amdgcn_permlane16_swap(xu, xu, false, false);
  return __uint_as_float(rp[0]) + __uint_as_float(rp[1]);
#else
  return x + __shfl_xor(x, 16, 64);
#endif
}
__device__ __forceinline__ float pairsum32(float x) {
#if __has_builtin(__builtin_amdgcn_permlane32_swap)
  unsigned xu = __float_as_uint(x);
  auto rp = __builtin_amdgcn_permlane32_swap(xu, xu, false, false);
  return __uint_as_float(rp[0]) + __uint_as_float(rp[1]);
#else
  return x + __shfl_xor(x, 32, 64);
#endif
}

__device__ __forceinline__ h2 bch2(unsigned u) { return __builtin_bit_cast(h2, u); }

// 64x64 matvec: gather packed pairs via DPP, 32 dot2 (8 chains depth 4),
// permlane transpose-reduce, select q == r.
__device__ __forceinline__ float matvec64d(float sval, const h2 (&ep)[4][8],
                                           int r) {
  float s1 = __uint_as_float(roru<1>(__float_as_uint(sval)));
  unsigned u0 = __builtin_bit_cast(unsigned, pkrtz(sval, s1));
  unsigned u1 = roru<2>(u0);
  unsigned u2 = roru<4>(u0);
  unsigned u3 = roru<6>(u0);
  unsigned u4 = roru<8>(u0);
  unsigned u5 = roru<10>(u0);
  unsigned u6 = roru<12>(u0);
  unsigned u7 = roru<14>(u0);
  float F0, F1, F2, F3;
#define DOTQ(Q, DST)                              \
  {                                               \
    float a = dot2f(bch2(u0), ep[Q][0], 0.0f);    \
    a = dot2f(bch2(u1), ep[Q][1], a);             \
    a = dot2f(bch2(u2), ep[Q][2], a);             \
    a = dot2f(bch2(u3), ep[Q][3], a);             \
    float b = dot2f(bch2(u4), ep[Q][4], 0.0f);    \
    b = dot2f(bch2(u5), ep[Q][5], b);             \
    b = dot2f(bch2(u6), ep[Q][6], b);             \
    b = dot2f(bch2(u7), ep[Q][7], b);             \
    DST = a + b;                                  \
  }
  DOTQ(0, F0) DOTQ(1, F1) DOTQ(2, F2) DOTQ(3, F3)
#undef DOTQ
  F0 = pairsum32(pairsum16(F0));
  F1 = pairsum32(pairsum16(F1));
  F2 = pairsum32(pairsum16(F2));
  F3 = pairsum32(pairsum16(F3));
  float ya = (r & 1) ? F1 : F0;
  float yb = (r & 1) ? F3 : F2;
  return (r & 2) ? yb : ya;
}

__global__
__attribute__((amdgpu_flat_work_group_size(128, 128), amdgpu_waves_per_eu(1, 1)))
void crf_nll_kernel(
    const float* __restrict__ emission,     // B,T,L
    const int*   __restrict__ target,       // B,T
    const float* __restrict__ mask,         // B,T
    const float* __restrict__ start_trans,  // L
    const float* __restrict__ trans,        // L,L
    const float* __restrict__ end_trans,    // L
    float* __restrict__ out)
{
  const int b = blockIdx.x;
  const int tid = threadIdx.x;
  const int wv = tid >> 6;            // 0 = forward, 1 = backward
  const int j = tid & 63;
  const int r = j >> 4;
  const int c = j & 15;

  const float* em_b = emission + (size_t)b * NT * NL;
  const float* mk_b = mask + (size_t)b * NT;
  const int*   tg_b = target + (size_t)b * NT;

  __shared__ float fF[NL], fB[NL];
  __shared__ float psS[2];
  __shared__ int   GS[2];

  // ---- probe the gather permutation. Pair m of the packed-DPP net holds
  // ---- (s[e0x[m]], s[e1x[m]]) with e0x[m] = sig2m(c), e1x[m] = sig1(sig2m(c)).
  int e0x[8], e1x[8];
  {
    unsigned cu = (unsigned)c;
    unsigned c1 = roru<1>(cu);
    e0x[0] = (int)cu;  e1x[0] = (int)c1;
#define PRB(M) e0x[M] = (int)roru<2 * M>(cu); e1x[M] = (int)roru<2 * M>(c1);
    PRB(1) PRB(2) PRB(3) PRB(4) PRB(5) PRB(6) PRB(7)
#undef PRB
  }

  // ------- path score: wave wv covers chunks [4wv, 4wv+4) = its T half -----
  float ps = 0.0f;
  #pragma unroll
  for (int cc = 4 * wv; cc < 4 * wv + 4; ++cc) {
    int t = cc * 64 + j;
    int cur = tg_b[t];
    float m  = mk_b[t];
    float mn = (t + 1 < NT) ? mk_b[t + 1] : 0.0f;
    if (t == 0) {
      ps += start_trans[cur] + em_b[cur];
    } else {
      int prev = tg_b[t - 1];
      if (m > 0.5f)
        ps += trans[prev * NL + cur] + em_b[(size_t)t * NL + cur];
      if (m - mn > 0.5f)                 // end_mask = m_t & !m_{t+1}
        ps += end_trans[cur];
    }
  }
  #pragma unroll
  for (int off = 32; off; off >>= 1) ps += __shfl_down(ps, off, 64);

  const float endt = __builtin_amdgcn_exp2f(L2E * end_trans[j]);

  int G = 0;          // exact integer scale deficit (log2 units): true = s*2^G
  float s;

  if (wv == 0) {
    // ======================= FORWARD: t = 0..255 ===========================
    // y = E^T s: ep[q][m] = h2(exp(trans[16r+e0x[m]][16q+c]),
    //                          exp(trans[16r+e1x[m]][16q+c]))
    h2 ep[4][8];
    #pragma unroll
    for (int q = 0; q < 4; ++q) {
      const int col = 16 * q + c;
      #pragma unroll
      for (int m = 0; m < 8; ++m) {
        float e0 = __builtin_amdgcn_exp2f(L2E * trans[(16 * r + e0x[m]) * NL + col]);
        float e1 = __builtin_amdgcn_exp2f(L2E * trans[(16 * r + e1x[m]) * NL + col]);
        h2 v; v[0] = (_Float16)e0; v[1] = (_Float16)e1;
        ep[q][m] = v;
      }
    }
    s = __builtin_amdgcn_exp2f(L2E * (start_trans[j] + em_b[j]));  // t=0

    // raw prefetch ring: pfr[u] = em[t][j] for upcoming step t (t&7 == u)
    float pfr[8];
    #pragma unroll
    for (int u = 0; u < 8; ++u) pfr[u] = em_b[(size_t)u * NL + j];

    float mlv = mk_b[j];
    float mnv = mk_b[j + 1];

    #pragma unroll 1
    for (int cc = 0; cc < 4; ++cc) {
      const int tb = cc * 64;
      unsigned long long cm = __ballot(mlv > 0.5f);
      unsigned long long ce = __ballot(mlv - mnv > 0.5f);
      if (cc == 0) { cm &= ~1ull; ce &= ~1ull; }  // t=0 handled by init
      mlv = mk_b[tb + 64 + j];          // next block (max 320 < NT)
      mnv = mk_b[tb + 64 + j + 1];

      #pragma unroll 1
      for (int i8 = 0; i8 < 64; i8 += 8) {
        #pragma unroll
        for (int u = 0; u < 8; ++u) {
          const int i = i8 + u;
          const int t = tb + i;
          float pv = pfr[u];
          pfr[u] = em_b[(size_t)(t + 8) * NL + j];   // t+8 <= 263 < NT
          float eemu = __builtin_amdgcn_exp2f(L2E * pv);
          eemu = ((ce >> i) & 1) ? eemu * endt : eemu;
          // chain: packed-DPP matvec -> exact rescale -> select
          float sm = matvec64d(s, ep, r);
          unsigned e0 =
            (__builtin_amdgcn_readfirstlane(__float_as_uint(sm)) >> 23) & 0xffu;
          float scale = __uint_as_float((254u - e0) << 23);  // 2^(127-e0)
          float snew = (sm * scale) * eemu;
          float sold = s * scale;
          s = ((cm >> i) & 1) ? snew : sold;
          G += (int)e0 - 127;
        }
      }
    }
  } else {
    // ======================= BACKWARD: t = 511..256 ========================
    // v' = E (v o w): ep[q][m] = h2(exp(trans[16q+c][16r+e0x[m]]),
    //                               exp(trans[16q+c][16r+e1x[m]]))
    h2 ep[4][8];
    #pragma unroll
    for (int q = 0; q < 4; ++q) {
      const int rowi = 16 * q + c;
      #pragma unroll
      for (int m = 0; m < 8; ++m) {
        float e0 = __builtin_amdgcn_exp2f(L2E * trans[rowi * NL + 16 * r + e0x[m]]);
        float e1 = __builtin_amdgcn_exp2f(L2E * trans[rowi * NL + 16 * r + e1x[m]]);
        h2 v; v[0] = (_Float16)e0; v[1] = (_Float16)e1;
        ep[q][m] = v;
      }
    }
    s = 1.0f;                                   // v^T = 1^T

    float pfr[8];                                // slot t&7; boots 511..504
    #pragma unroll
    for (int u = 0; u < 8; ++u) pfr[u] = em_b[(size_t)(504 + u) * NL + j];

    float mlv = mk_b[448 + j];
    int nidx0 = 448 + j + 1;
    float mnv = (nidx0 < NT) ? mk_b[nidx0] : 0.0f;

    #pragma unroll 1
    for (int cc = 7; cc >= 4; --cc) {
      const int tb = cc * 64;
      unsigned long long cm = __ballot(mlv > 0.5f);
      unsigned long long ce = __ballot(mlv - mnv > 0.5f);
      mlv = mk_b[tb - 64 + j];          // prev block (min 192, max 256 < NT)
      mnv = mk_b[tb - 64 + j + 1];

      #pragma unroll 1
      for (int i8 = 56; i8 >= 0; i8 -= 8) {
        #pragma unroll
        for (int u = 7; u >= 0; --u) {
          const int i = i8 + u;
          const int t = tb + i;                  // t & 7 == u
          float pv = pfr[u];
          pfr[u] = em_b[(size_t)(t - 8) * NL + j];   // t-8 >= 248
          float eemu = __builtin_amdgcn_exp2f(L2E * pv);
          float wmul = ((cm >> i) & 1) ? eemu : 1.0f;
          wmul = ((ce >> i) & 1) ? wmul * endt : wmul;
          float w = s * wmul;
          if ((cm >> i) & 1) {
            float sm = matvec64d(w, ep, r);
            unsigned e0 =
              (__builtin_amdgcn_readfirstlane(__float_as_uint(sm)) >> 23) & 0xffu;
            float scale = __uint_as_float((254u - e0) << 23);  // 2^(127-e0)
            s = sm * scale;
            G += (int)e0 - 127;
          } else {
            s = w;                               // A_t = I (masked-out step)
          }
        }
      }
    }
  }

  // ---------------- junction: norm = log(v . q) + (Gf+Gb)*ln2 ---------------
  if (wv == 0) { fF[j] = s; if (j == 0) { psS[0] = ps; GS[0] = G; } }
  else         { fB[j] = s; if (j == 0) { psS[1] = ps; GS[1] = G; } }
  __syncthreads();
  if (wv == 0) {
    float prod = s * fB[j];
    #pragma unroll
    for (int off = 32; off; off >>= 1) prod += __shfl_xor(prod, off, 64);
    if (j == 0) {
      float norm = (__builtin_amdgcn_logf(prod) + (float)(GS[0] + GS[1])) * LN2;
      atomicAdd(out, (norm - psS[0] - psS[1]) * (1.0f / (float)NB));
    }
  }
}

extern "C" void kernel_launch(void* const* d_in, const int* in_sizes, int n_in,
                              void* d_out, int out_size, void* d_ws, size_t ws_size,
                              hipStream_t stream) {
  const float* emission    = (const float*)d_in[0];
  const int*   target      = (const int*)  d_in[1];
  const float* mask        = (const float*)d_in[2];
  const float* start_trans = (const float*)d_in[3];
  const float* trans       = (const float*)d_in[4];
  const float* end_trans   = (const float*)d_in[5];
  float* out = (float*)d_out;

  zero_out_kernel<<<1, 1, 0, stream>>>(out);
  crf_nll_kernel<<<NB, 128, 0, stream>>>(emission, target, mask, start_trans,
                                         trans, end_trans, out);
}